// Round 8
// baseline (353.076 us; speedup 1.0000x reference)
//
#include <hip/hip_runtime.h>
#include <hip/hip_bf16.h>

// GCN encoder: 3 layers on N=100000 nodes, E=1250000 edges, 64 features.
// gcn(x) = relu(D^-1/2 (A+I) D^-1/2 (xW) + b)
// Folding: hs = dinv .* (xW);  agg[d] = hs[d] + sum_{s->d} hs[s];
//          next layer's GEMM applies relu(dinv[d]*agg + b) as its pre-transform.
// R1..R8: dst-CSR gather reduction, bucketed 2-phase CSR build, bf16 hs,
//         split-bf16 MFMA GEMM (fp32-accurate), LDS-staged csr_local.
// R9 (REVERTED): agg+gemm fusion regressed (latency-bound kernels: traffic
//         cuts don't pay, parallelism does).
// R10: eighth-wave uint4 aggregate; 32b packed pairs; BSHIFT 8.
// R11: bcur_init -> hipMemsetAsync; bsum_scan folded into csr_local;
//      partition PCHUNK 3072.
// R12: aggregate MLP was ~2-4 (VGPR_Count=12 at R2: compiler serialized the
//      guarded load+acc). Now explicit 8-edge register batches: 8 exec-masked
//      gathers into vv[8] (zero-init), THEN accumulate the batch (zero-adds
//      for masked slots; ascending-k order = bitwise identical). First acc
//      waits vmcnt(7), not vmcnt(0). __launch_bounds__(256,8) pins VGPR<=64
//      (8 waves/SIMD). Nontemporal hints on stream-once traffic.
// R13: compile fix — __builtin_nontemporal_* rejects HIP_vector_type
//      (float4 is a class); use clang ext_vector f32x4 for the hinted 16B
//      accesses. Logic identical to R12.

#define WG 256
#define BSHIFT 8                 // 256 nodes per bucket
#define BSIZE  (1 << BSHIFT)
#define NBK_MAX 512
#define BCAP   4096              // pair slots per bucket (mean 3200, sd ~57)
#define PCHUNK 3072              // edges per partition block (12 per thread)
#define WT_LD  72                // transposed-W LDS leading dim (bf16 elems)

typedef __attribute__((ext_vector_type(8))) short bf16x8;
typedef __attribute__((ext_vector_type(4))) float f32x4;
typedef __attribute__((ext_vector_type(4))) unsigned u32x4;

__device__ __forceinline__ unsigned short f2bf(float f) {
    union { float f; unsigned u; } v; v.f = f;
    unsigned r = v.u + 0x7fffu + ((v.u >> 16) & 1u);   // RNE
    return (unsigned short)(r >> 16);
}
__device__ __forceinline__ float bf2f(unsigned short h) {
    union { unsigned u; float f; } v; v.u = ((unsigned)h) << 16;
    return v.f;
}
__device__ __forceinline__ void acc_bf16x2(float& a, float& b, unsigned u) {
    union { unsigned v; float f; } lo, hi;
    lo.v = u << 16;
    hi.v = u & 0xffff0000u;
    a += lo.f;
    b += hi.f;
}

// Partition edges by dst-bucket into packed pairs ((dst&255)<<17 | src) in
// fixed per-bucket slabs. cur2[b] holds the bucket COUNT (memset 0 before);
// slab position = b*BCAP + count. LDS histogram -> one global atomic per
// touched bucket -> stage (pair,dest) in LDS in bucket-slot order -> linear
// output loop: consecutive threads write consecutive dests per bucket run.
__global__ __launch_bounds__(WG) void partition(const int* __restrict__ ei,
                                                int* __restrict__ cur2,
                                                unsigned* __restrict__ pairs,
                                                int E) {
    __shared__ int hist[NBK_MAX];
    __shared__ int gbase[NBK_MAX];
    __shared__ int lb[NBK_MAX];
    __shared__ int wsum4[4];
    __shared__ unsigned sp[PCHUNK];
    __shared__ int sd[PCHUNK];
    const int t = threadIdx.x;
    const int lane = t & 63;
    const int w = t >> 6;
    const int base = blockIdx.x * PCHUNK;
    const int total = min(PCHUNK, E - base);

    hist[t] = 0;
    hist[t + 256] = 0;
    __syncthreads();

    int s[12], d[12], r[12];
#pragma unroll
    for (int i = 0; i < 12; i++) {
        int e = base + i * WG + t;           // coalesced
        bool ok = e < E;
        s[i] = ok ? __builtin_nontemporal_load(ei + e) : 0;
        d[i] = ok ? __builtin_nontemporal_load(ei + E + e) : 0;
        r[i] = ok ? atomicAdd(&hist[d[i] >> BSHIFT], 1) : 0;
        if (!ok) d[i] = -1;
    }
    __syncthreads();

    // per-bucket global base (buckets t and t+256): slab offset + old count
    int hv0 = hist[t];
    int hv1 = hist[t + 256];
    if (hv0 > 0) gbase[t] = t * BCAP + atomicAdd(&cur2[t], hv0);
    if (hv1 > 0) gbase[t + 256] = (t + 256) * BCAP + atomicAdd(&cur2[t + 256], hv1);

    // exclusive scan of hist[0..511] -> lb: thread t owns pair (2t, 2t+1)
    int a0 = hist[2 * t];
    int a1 = hist[2 * t + 1];
    int ps = a0 + a1;
    int sc = ps;
#pragma unroll
    for (int ofs = 1; ofs < 64; ofs <<= 1) {
        int u = __shfl_up(sc, ofs);
        if (lane >= ofs) sc += u;
    }
    if (lane == 63) wsum4[w] = sc;
    __syncthreads();
    if (t == 0) {
        int run = 0;
#pragma unroll
        for (int i = 0; i < 4; i++) { int x = wsum4[i]; wsum4[i] = run; run += x; }
    }
    __syncthreads();
    int excl = sc + wsum4[w] - ps;
    lb[2 * t] = excl;
    lb[2 * t + 1] = excl + a0;
    __syncthreads();

#pragma unroll
    for (int i = 0; i < 12; i++) {
        if (d[i] >= 0) {
            int b = d[i] >> BSHIFT;
            int slot = lb[b] + r[i];
            sp[slot] = ((unsigned)(d[i] & (BSIZE - 1)) << 17) | (unsigned)s[i];
            sd[slot] = gbase[b] + r[i];
        }
    }
    __syncthreads();

    for (int j = t; j < total; j += WG)
        pairs[sd[j]] = sp[j];
}

// Per-bucket CSR. Entry: every block shfl-scans the 512 bucket counts (cur2)
// to get its own global base (replaces the bsum_scan dispatch; block 0 also
// writes off[N]=E). Then: stage packed pairs (16KB) + bucket-local csr
// (16KB) in LDS, LDS hist/scatter, coalesced write-out. 391 blocks x 512
// threads, ~36KB LDS -> 4 blocks/CU.
__global__ __launch_bounds__(512) void csr_local(const unsigned* __restrict__ pairs,
                                                 const int* __restrict__ cur2,
                                                 int* __restrict__ off,
                                                 float* __restrict__ dinv,
                                                 int* __restrict__ csr,
                                                 int N, int nbk) {
    __shared__ unsigned sp[BCAP];             // 16 KB staged pairs
    __shared__ int cs[BCAP];                  // 16 KB bucket-local csr
    __shared__ int h[BSIZE];
    __shared__ int cur[BSIZE];
    __shared__ int bb[NBK_MAX];               // 2 KB exclusive bucket bases
    __shared__ int wsum8[8];
    __shared__ int wsum4[4];
    const int b = blockIdx.x;
    const int t = threadIdx.x;
    const int lane = t & 63;
    const int w = t >> 6;
    const int node0 = b << BSHIFT;
    const int nlocal = min(BSIZE, N - node0);
    const int pstart = b * BCAP;
    const int cnt = cur2[b];                  // count (memset-0 + atomics)

    // ---- bucket-base scan (all 512 counts), replaces bsum_scan ----
    int cval = (t < nbk) ? cur2[t] : 0;
    int sc2 = cval;
#pragma unroll
    for (int ofs = 1; ofs < 64; ofs <<= 1) {
        int u = __shfl_up(sc2, ofs);
        if (lane >= ofs) sc2 += u;
    }
    if (lane == 63) wsum8[w] = sc2;
    if (t < BSIZE) h[t] = 0;                  // hist init (no extra barrier)
    __syncthreads();
    if (t == 0) {
        int run = 0;
#pragma unroll
        for (int i = 0; i < 8; i++) { int x = wsum8[i]; wsum8[i] = run; run += x; }
    }
    __syncthreads();
    bb[t] = sc2 + wsum8[w] - cval;            // exclusive prefix
    if (b == 0 && t == 511) off[N] = sc2 + wsum8[7];   // total = E
    __syncthreads();
    const int base = bb[b];

    // ---- stage pairs + histogram ----
    for (int e = t; e < cnt; e += 512) {      // only global pairs read
        unsigned p = __builtin_nontemporal_load(pairs + pstart + e);
        sp[e] = p;
        atomicAdd(&h[p >> 17], 1);
    }
    __syncthreads();

    // scan h[0..255]: waves 0..3 shfl scan + cross-wave fixup
    int myh = (t < BSIZE) ? h[t] : 0;
    int sc = myh;
#pragma unroll
    for (int d = 1; d < 64; d <<= 1) {
        int u = __shfl_up(sc, d);
        if (lane >= d) sc += u;
    }
    if (t < BSIZE && lane == 63) wsum4[w] = sc;
    __syncthreads();
    if (t == 0) {
        int run = 0;
#pragma unroll
        for (int i = 0; i < 4; i++) { int x = wsum4[i]; wsum4[i] = run; run += x; }
    }
    __syncthreads();
    if (t < BSIZE) {
        int excl = sc + wsum4[w] - myh;       // bucket-local exclusive prefix
        cur[t] = excl;
        if (t < nlocal) {
            off[node0 + t] = base + excl;
            dinv[node0 + t] = rsqrtf((float)(myh + 1));
        }
    }
    __syncthreads();

    for (int e = t; e < cnt; e += 512) {      // LDS scatter
        unsigned p = sp[e];
        int pos = atomicAdd(&cur[p >> 17], 1);
        cs[pos] = (int)(p & 0x1ffffu);
    }
    __syncthreads();

    for (int j = t; j < cnt; j += 512)        // coalesced write-out
        csr[base + j] = cs[j];
}

// Fused GEMM via split-bf16 MFMA: out = post( pre(in) @ W )
//   pre(v)  = pre_flag ? relu(dinv[row]*v + b_pre[col]) : v
//   post(a) = (post_scale ? dinv[row]*a : a) + (b_post ? b_post[col] : 0)
// Block = 64 rows x 64 cols, 4 waves x 16 rows; A-frags from global with
// pre-transform in fp32, split to bf16 hi/lo; W staged transposed hi/lo in
// LDS; 4 MFMAs per (ct,kc) reproduce fp32 accuracy at matrix-core rate.
__global__ __launch_bounds__(WG, 4) void gemm_fused(
    const float* __restrict__ in, const float* __restrict__ W,
    const float* __restrict__ dinv, const float* __restrict__ b_pre, int pre_flag,
    int post_scale, const float* __restrict__ b_post,
    void* __restrict__ out1, int out_bf16, int n_rows)
{
    __shared__ __align__(16) short Wh[64 * WT_LD];
    __shared__ __align__(16) short Wl[64 * WT_LD];

    const int t = threadIdx.x;

    // stage W transposed, split hi/lo bf16 (Wt[j][k], j = output col)
    const float4* W4 = (const float4*)W;
#pragma unroll
    for (int i = 0; i < 4; i++) {
        int q = i * WG + t;              // float4 index, 1024 total
        float4 w = W4[q];
        int base = q * 4;
        int k = base >> 6;
        int j0 = base & 63;
        float wf[4] = {w.x, w.y, w.z, w.w};
#pragma unroll
        for (int e = 0; e < 4; e++) {
            unsigned short h = f2bf(wf[e]);
            Wh[(j0 + e) * WT_LD + k] = (short)h;
            Wl[(j0 + e) * WT_LD + k] = (short)f2bf(wf[e] - bf2f(h));
        }
    }

    const int wid = t >> 6;              // wave 0..3
    const int l = t & 63;
    const int lr = l & 15;
    const int lk = l >> 4;
    const int row0 = blockIdx.x * 64 + wid * 16;
    const int arow = row0 + lr;
    const int srow = (arow < n_rows) ? arow : 0;   // safe row for loads

    // A fragments: 2 k-chunks of 32, pre-transform + hi/lo split
    bf16x8 ah[2], al[2];
    float dv = pre_flag ? dinv[srow] : 0.f;
#pragma unroll
    for (int kc = 0; kc < 2; kc++) {
        const float* p = in + (size_t)srow * 64 + kc * 32 + lk * 8;
        f32x4 v0 = __builtin_nontemporal_load((const f32x4*)p);
        f32x4 v1 = __builtin_nontemporal_load((const f32x4*)(p + 4));
        float vv[8] = {v0[0], v0[1], v0[2], v0[3], v1[0], v1[1], v1[2], v1[3]};
        if (pre_flag) {
            const float* bp = b_pre + kc * 32 + lk * 8;
            float4 b0 = *(const float4*)bp;
            float4 b1 = *(const float4*)(bp + 4);
            float bb[8] = {b0.x, b0.y, b0.z, b0.w, b1.x, b1.y, b1.z, b1.w};
#pragma unroll
            for (int e = 0; e < 8; e++)
                vv[e] = fmaxf(fmaf(dv, vv[e], bb[e]), 0.f);
        }
#pragma unroll
        for (int e = 0; e < 8; e++) {
            unsigned short h = f2bf(vv[e]);
            ah[kc][e] = (short)h;
            al[kc][e] = (short)f2bf(vv[e] - bf2f(h));
        }
    }

    __syncthreads();

    f32x4 acc[4] = {};
#pragma unroll
    for (int ct = 0; ct < 4; ct++) {
#pragma unroll
        for (int kc = 0; kc < 2; kc++) {
            const short* ph = &Wh[(ct * 16 + lr) * WT_LD + kc * 32 + lk * 8];
            const short* pl = &Wl[(ct * 16 + lr) * WT_LD + kc * 32 + lk * 8];
            bf16x8 bh = *(const bf16x8*)ph;
            bf16x8 bl = *(const bf16x8*)pl;
            acc[ct] = __builtin_amdgcn_mfma_f32_16x16x32_bf16(ah[kc], bh, acc[ct], 0, 0, 0);
            acc[ct] = __builtin_amdgcn_mfma_f32_16x16x32_bf16(al[kc], bh, acc[ct], 0, 0, 0);
            acc[ct] = __builtin_amdgcn_mfma_f32_16x16x32_bf16(ah[kc], bl, acc[ct], 0, 0, 0);
            acc[ct] = __builtin_amdgcn_mfma_f32_16x16x32_bf16(al[kc], bl, acc[ct], 0, 0, 0);
        }
    }

    // store: D[row = row0 + lk*4 + r][col = ct*16 + lr]  (m89-verified C/D map)
#pragma unroll
    for (int r = 0; r < 4; r++) {
        int orow = row0 + lk * 4 + r;
        if (orow >= n_rows) continue;
        float sc = post_scale ? dinv[orow] : 1.0f;
#pragma unroll
        for (int ct = 0; ct < 4; ct++) {
            float bpv = b_post ? b_post[ct * 16 + lr] : 0.f;
            float o = fmaf(acc[ct][r], sc, bpv);
            if (out_bf16) {
                ((unsigned short*)out1)[((size_t)orow << 6) + ct * 16 + lr] = f2bf(o);
            } else {
                // final layer: out never re-read -> nontemporal
                __builtin_nontemporal_store(o,
                    (float*)out1 + ((size_t)orow << 6) + ct * 16 + lr);
            }
        }
    }
}

// Segmented reduction over dst-CSR: B[d] = A[d] + sum A[csr[e]]  (A is bf16).
// Eighth-wave (8 lanes) per node: lane owns uint4 (8 bf16 cols) of the row.
// Edge loop in explicit 8-edge register batches: 8 exec-masked gathers into
// vv[8] (zero-init), THEN accumulate (zero-adds for masked slots; ascending
// k = bitwise-identical order). Guarantees 8 loads in flight per wave (first
// acc waits vmcnt(7)). launch_bounds(256,8) pins VGPR<=64 -> 8 waves/SIMD.
__global__ __launch_bounds__(WG, 8) void aggregate(
    const uint4* __restrict__ A8, float* __restrict__ B,
    const int* __restrict__ off, const int* __restrict__ csr, int N)
{
    const int t = threadIdx.x;
    const int l = t & 63;
    const int c = l & 7;            // uint4 col (8 bf16 values)
    const int g = l >> 3;           // eighth = node sub-slot
    int node = blockIdx.x * 32 + ((t >> 6) << 3) + g;
    const bool valid = node < N;
    if (!valid) node = N - 1;

    const int s0 = off[node];
    const int s1 = valid ? off[node + 1] : s0;

    uint4 v = A8[((size_t)node << 3) + c];          // self-loop row
    float a0 = 0.f, a1 = 0.f, a2 = 0.f, a3 = 0.f;
    float a4 = 0.f, a5 = 0.f, a6 = 0.f, a7 = 0.f;
    acc_bf16x2(a0, a1, v.x);
    acc_bf16x2(a2, a3, v.y);
    acc_bf16x2(a4, a5, v.z);
    acc_bf16x2(a6, a7, v.w);

    for (int p = s0; p < s1; p += 32) {
        const int rem = s1 - p;
        int idx[4];
#pragma unroll
        for (int q = 0; q < 4; q++)
            idx[q] = (8 * q + c < rem) ?
                     __builtin_nontemporal_load(csr + p + 8 * q + c) : 0;
#pragma unroll
        for (int kb = 0; kb < 32; kb += 8) {
            if (kb < rem) {                   // batch live for this group?
                uint4 vv[8];
#pragma unroll
                for (int j = 0; j < 8; j++) {  // 8 gathers issued back-to-back
                    int k = kb + j;
                    int src = __shfl(idx[k >> 3], (g << 3) + (k & 7));
                    vv[j] = make_uint4(0u, 0u, 0u, 0u);
                    if (k < rem) vv[j] = A8[((size_t)src << 3) + c];
                }
#pragma unroll
                for (int j = 0; j < 8; j++) {  // dense accumulate (zero-adds ok)
                    acc_bf16x2(a0, a1, vv[j].x);
                    acc_bf16x2(a2, a3, vv[j].y);
                    acc_bf16x2(a4, a5, vv[j].z);
                    acc_bf16x2(a6, a7, vv[j].w);
                }
            }
        }
    }

    if (valid) {
        float* bp = B + ((size_t)node << 6) + 8 * c;
        f32x4 o0 = {a0, a1, a2, a3};
        f32x4 o1 = {a4, a5, a6, a7};
        __builtin_nontemporal_store(o0, (f32x4*)bp);
        __builtin_nontemporal_store(o1, (f32x4*)(bp + 4));
    }
}

extern "C" void kernel_launch(void* const* d_in, const int* in_sizes, int n_in,
                              void* d_out, int out_size, void* d_ws, size_t ws_size,
                              hipStream_t stream) {
    const float* x  = (const float*)d_in[0];
    const int*   ei = (const int*)d_in[1];
    const float* W1 = (const float*)d_in[2];
    const float* b1 = (const float*)d_in[3];
    const float* W2 = (const float*)d_in[4];
    const float* b2 = (const float*)d_in[5];
    const float* W3 = (const float*)d_in[6];
    const float* b3 = (const float*)d_in[7];
    float* out = (float*)d_out;

    const int N = in_sizes[0] / 64;    // 100000
    const int E = in_sizes[1] / 2;     // 1250000
    const int nbk = (N + BSIZE - 1) / BSIZE;        // 391 buckets

    // workspace layout
    int*   off  = (int*)d_ws;                       // N+1
    int*   csr  = off + (N + 1);                    // E
    int*   cur2 = csr + E;                          // 512 (bucket counts)
    uintptr_t pa = (uintptr_t)(cur2 + 512);
    pa = (pa + 255) & ~(uintptr_t)255;
    float* dinv = (float*)pa;                       // N
    __hip_bfloat16* A = (__hip_bfloat16*)(dinv + N);// N*64 bf16 (hs)
    float* B    = (float*)(A + (size_t)N * 64);     // N*64 fp32 (agg)
    unsigned* pairs = (unsigned*)B;                 // aliased: dead until agg1
                                                    // nbk*BCAP*4 = 6.4MB <= 25.6MB

    const int gG = (N + 63) / 64;
    const int gA = (N + 31) / 32;
    const int gP = (E + PCHUNK - 1) / PCHUNK;

    // CSR build (per call; ws re-poisoned every launch)
    (void)hipMemsetAsync(cur2, 0, 512 * sizeof(int), stream);
    partition<<<gP,  WG, 0, stream>>>(ei, cur2, pairs, E);
    csr_local<<<nbk, 512, 0, stream>>>(pairs, cur2, off, dinv, csr, N, nbk);

    // Layer 1: A = bf16(dinv.*(x@W1)); B = A[d] + sum A[src]
    gemm_fused<<<gG, WG, 0, stream>>>(x, W1, dinv, nullptr, 0, 1, nullptr, A, 1, N);
    aggregate <<<gA, WG, 0, stream>>>((const uint4*)A, B, off, csr, N);

    // Layer 2: in = B (pre: relu(dinv*v + b1)); A = bf16(dinv.*(h@W2)); B = agg
    gemm_fused<<<gG, WG, 0, stream>>>(B, W2, dinv, b1, 1, 1, nullptr, A, 1, N);
    aggregate <<<gA, WG, 0, stream>>>((const uint4*)A, B, off, csr, N);

    // Layer 3: in = B (pre: relu(dinv*v + b2)); out = h@W3 + b3 (fp32)
    gemm_fused<<<gG, WG, 0, stream>>>(B, W3, dinv, b2, 1, 0, b3, out, 0, N);
}

// Round 9
// 309.137 us; speedup vs baseline: 1.1421x; 1.1421x over previous
//
#include <hip/hip_runtime.h>
#include <hip/hip_bf16.h>

// GCN encoder: 3 layers on N=100000 nodes, E=1250000 edges, 64 features.
// gcn(x) = relu(D^-1/2 (A+I) D^-1/2 (xW) + b)
// Folding: hs = dinv .* (xW);  agg[d] = hs[d] + sum_{s->d} hs[s];
//          next layer's GEMM applies relu(dinv[d]*agg + b) as its pre-transform.
// R1..R8: dst-CSR gather reduction, bucketed 2-phase CSR build, bf16 hs,
//         split-bf16 MFMA GEMM (fp32-accurate), LDS-staged csr_local.
// R9 (REVERTED): agg+gemm fusion (latency-bound: parallelism > traffic cuts).
// R10: eighth-wave uint4 aggregate; 32b packed pairs; BSHIFT 8.
// R11: memset-based cursors; bsum_scan folded into csr_local; PCHUNK 3072.
// R12/R13 (NT REVERTED): nontemporal stores on lane-interleaved 16B chunks
//         bypass L2 write-coalescing -> HBM partial-line RMW: WRITE 25->140MB,
//         FETCH 69.8->135MB, aggregate 28->96us. NEVER nt-store sub-line
//         interleaved data on gfx950. All NT hints removed.
// R14: keep (only) the R12 register batching, now cleanly isolated: 8-edge
//      batches of exec-masked gathers into vv[8], then dense accumulate
//      (ascending k = bitwise-identical order). First acc waits vmcnt(7) ->
//      guaranteed 8 loads in flight/wave. launch_bounds(256,8), VGPR<=64.

#define WG 256
#define BSHIFT 8                 // 256 nodes per bucket
#define BSIZE  (1 << BSHIFT)
#define NBK_MAX 512
#define BCAP   4096              // pair slots per bucket (mean 3200, sd ~57)
#define PCHUNK 3072              // edges per partition block (12 per thread)
#define WT_LD  72                // transposed-W LDS leading dim (bf16 elems)

typedef __attribute__((ext_vector_type(8))) short bf16x8;
typedef __attribute__((ext_vector_type(4))) float f32x4;

__device__ __forceinline__ unsigned short f2bf(float f) {
    union { float f; unsigned u; } v; v.f = f;
    unsigned r = v.u + 0x7fffu + ((v.u >> 16) & 1u);   // RNE
    return (unsigned short)(r >> 16);
}
__device__ __forceinline__ float bf2f(unsigned short h) {
    union { unsigned u; float f; } v; v.u = ((unsigned)h) << 16;
    return v.f;
}
__device__ __forceinline__ void acc_bf16x2(float& a, float& b, unsigned u) {
    union { unsigned v; float f; } lo, hi;
    lo.v = u << 16;
    hi.v = u & 0xffff0000u;
    a += lo.f;
    b += hi.f;
}

// Partition edges by dst-bucket into packed pairs ((dst&255)<<17 | src) in
// fixed per-bucket slabs. cur2[b] holds the bucket COUNT (memset 0 before);
// slab position = b*BCAP + count. LDS histogram -> one global atomic per
// touched bucket -> stage (pair,dest) in LDS in bucket-slot order -> linear
// output loop: consecutive threads write consecutive dests per bucket run.
__global__ __launch_bounds__(WG) void partition(const int* __restrict__ ei,
                                                int* __restrict__ cur2,
                                                unsigned* __restrict__ pairs,
                                                int E) {
    __shared__ int hist[NBK_MAX];
    __shared__ int gbase[NBK_MAX];
    __shared__ int lb[NBK_MAX];
    __shared__ int wsum4[4];
    __shared__ unsigned sp[PCHUNK];
    __shared__ int sd[PCHUNK];
    const int t = threadIdx.x;
    const int lane = t & 63;
    const int w = t >> 6;
    const int base = blockIdx.x * PCHUNK;
    const int total = min(PCHUNK, E - base);

    hist[t] = 0;
    hist[t + 256] = 0;
    __syncthreads();

    int s[12], d[12], r[12];
#pragma unroll
    for (int i = 0; i < 12; i++) {
        int e = base + i * WG + t;           // coalesced
        bool ok = e < E;
        s[i] = ok ? ei[e] : 0;
        d[i] = ok ? ei[E + e] : 0;
        r[i] = ok ? atomicAdd(&hist[d[i] >> BSHIFT], 1) : 0;
        if (!ok) d[i] = -1;
    }
    __syncthreads();

    // per-bucket global base (buckets t and t+256): slab offset + old count
    int hv0 = hist[t];
    int hv1 = hist[t + 256];
    if (hv0 > 0) gbase[t] = t * BCAP + atomicAdd(&cur2[t], hv0);
    if (hv1 > 0) gbase[t + 256] = (t + 256) * BCAP + atomicAdd(&cur2[t + 256], hv1);

    // exclusive scan of hist[0..511] -> lb: thread t owns pair (2t, 2t+1)
    int a0 = hist[2 * t];
    int a1 = hist[2 * t + 1];
    int ps = a0 + a1;
    int sc = ps;
#pragma unroll
    for (int ofs = 1; ofs < 64; ofs <<= 1) {
        int u = __shfl_up(sc, ofs);
        if (lane >= ofs) sc += u;
    }
    if (lane == 63) wsum4[w] = sc;
    __syncthreads();
    if (t == 0) {
        int run = 0;
#pragma unroll
        for (int i = 0; i < 4; i++) { int x = wsum4[i]; wsum4[i] = run; run += x; }
    }
    __syncthreads();
    int excl = sc + wsum4[w] - ps;
    lb[2 * t] = excl;
    lb[2 * t + 1] = excl + a0;
    __syncthreads();

#pragma unroll
    for (int i = 0; i < 12; i++) {
        if (d[i] >= 0) {
            int b = d[i] >> BSHIFT;
            int slot = lb[b] + r[i];
            sp[slot] = ((unsigned)(d[i] & (BSIZE - 1)) << 17) | (unsigned)s[i];
            sd[slot] = gbase[b] + r[i];
        }
    }
    __syncthreads();

    for (int j = t; j < total; j += WG)
        pairs[sd[j]] = sp[j];
}

// Per-bucket CSR. Entry: every block shfl-scans the 512 bucket counts (cur2)
// to get its own global base (replaces the bsum_scan dispatch; block 0 also
// writes off[N]=E). Then: stage packed pairs (16KB) + bucket-local csr
// (16KB) in LDS, LDS hist/scatter, coalesced write-out. 391 blocks x 512
// threads, ~36KB LDS -> 4 blocks/CU.
__global__ __launch_bounds__(512) void csr_local(const unsigned* __restrict__ pairs,
                                                 const int* __restrict__ cur2,
                                                 int* __restrict__ off,
                                                 float* __restrict__ dinv,
                                                 int* __restrict__ csr,
                                                 int N, int nbk) {
    __shared__ unsigned sp[BCAP];             // 16 KB staged pairs
    __shared__ int cs[BCAP];                  // 16 KB bucket-local csr
    __shared__ int h[BSIZE];
    __shared__ int cur[BSIZE];
    __shared__ int bb[NBK_MAX];               // 2 KB exclusive bucket bases
    __shared__ int wsum8[8];
    __shared__ int wsum4[4];
    const int b = blockIdx.x;
    const int t = threadIdx.x;
    const int lane = t & 63;
    const int w = t >> 6;
    const int node0 = b << BSHIFT;
    const int nlocal = min(BSIZE, N - node0);
    const int pstart = b * BCAP;
    const int cnt = cur2[b];                  // count (memset-0 + atomics)

    // ---- bucket-base scan (all 512 counts), replaces bsum_scan ----
    int cval = (t < nbk) ? cur2[t] : 0;
    int sc2 = cval;
#pragma unroll
    for (int ofs = 1; ofs < 64; ofs <<= 1) {
        int u = __shfl_up(sc2, ofs);
        if (lane >= ofs) sc2 += u;
    }
    if (lane == 63) wsum8[w] = sc2;
    if (t < BSIZE) h[t] = 0;                  // hist init (no extra barrier)
    __syncthreads();
    if (t == 0) {
        int run = 0;
#pragma unroll
        for (int i = 0; i < 8; i++) { int x = wsum8[i]; wsum8[i] = run; run += x; }
    }
    __syncthreads();
    bb[t] = sc2 + wsum8[w] - cval;            // exclusive prefix
    if (b == 0 && t == 511) off[N] = sc2 + wsum8[7];   // total = E
    __syncthreads();
    const int base = bb[b];

    // ---- stage pairs + histogram ----
    for (int e = t; e < cnt; e += 512) {      // only global pairs read
        unsigned p = pairs[pstart + e];
        sp[e] = p;
        atomicAdd(&h[p >> 17], 1);
    }
    __syncthreads();

    // scan h[0..255]: waves 0..3 shfl scan + cross-wave fixup
    int myh = (t < BSIZE) ? h[t] : 0;
    int sc = myh;
#pragma unroll
    for (int d = 1; d < 64; d <<= 1) {
        int u = __shfl_up(sc, d);
        if (lane >= d) sc += u;
    }
    if (t < BSIZE && lane == 63) wsum4[w] = sc;
    __syncthreads();
    if (t == 0) {
        int run = 0;
#pragma unroll
        for (int i = 0; i < 4; i++) { int x = wsum4[i]; wsum4[i] = run; run += x; }
    }
    __syncthreads();
    if (t < BSIZE) {
        int excl = sc + wsum4[w] - myh;       // bucket-local exclusive prefix
        cur[t] = excl;
        if (t < nlocal) {
            off[node0 + t] = base + excl;
            dinv[node0 + t] = rsqrtf((float)(myh + 1));
        }
    }
    __syncthreads();

    for (int e = t; e < cnt; e += 512) {      // LDS scatter
        unsigned p = sp[e];
        int pos = atomicAdd(&cur[p >> 17], 1);
        cs[pos] = (int)(p & 0x1ffffu);
    }
    __syncthreads();

    for (int j = t; j < cnt; j += 512)        // coalesced write-out
        csr[base + j] = cs[j];
}

// Fused GEMM via split-bf16 MFMA: out = post( pre(in) @ W )
//   pre(v)  = pre_flag ? relu(dinv[row]*v + b_pre[col]) : v
//   post(a) = (post_scale ? dinv[row]*a : a) + (b_post ? b_post[col] : 0)
// Block = 64 rows x 64 cols, 4 waves x 16 rows; A-frags from global with
// pre-transform in fp32, split to bf16 hi/lo; W staged transposed hi/lo in
// LDS; 4 MFMAs per (ct,kc) reproduce fp32 accuracy at matrix-core rate.
__global__ __launch_bounds__(WG, 4) void gemm_fused(
    const float* __restrict__ in, const float* __restrict__ W,
    const float* __restrict__ dinv, const float* __restrict__ b_pre, int pre_flag,
    int post_scale, const float* __restrict__ b_post,
    void* __restrict__ out1, int out_bf16, int n_rows)
{
    __shared__ __align__(16) short Wh[64 * WT_LD];
    __shared__ __align__(16) short Wl[64 * WT_LD];

    const int t = threadIdx.x;

    // stage W transposed, split hi/lo bf16 (Wt[j][k], j = output col)
    const float4* W4 = (const float4*)W;
#pragma unroll
    for (int i = 0; i < 4; i++) {
        int q = i * WG + t;              // float4 index, 1024 total
        float4 w = W4[q];
        int base = q * 4;
        int k = base >> 6;
        int j0 = base & 63;
        float wf[4] = {w.x, w.y, w.z, w.w};
#pragma unroll
        for (int e = 0; e < 4; e++) {
            unsigned short h = f2bf(wf[e]);
            Wh[(j0 + e) * WT_LD + k] = (short)h;
            Wl[(j0 + e) * WT_LD + k] = (short)f2bf(wf[e] - bf2f(h));
        }
    }

    const int wid = t >> 6;              // wave 0..3
    const int l = t & 63;
    const int lr = l & 15;
    const int lk = l >> 4;
    const int row0 = blockIdx.x * 64 + wid * 16;
    const int arow = row0 + lr;
    const int srow = (arow < n_rows) ? arow : 0;   // safe row for loads

    // A fragments: 2 k-chunks of 32, pre-transform + hi/lo split
    bf16x8 ah[2], al[2];
    float dv = pre_flag ? dinv[srow] : 0.f;
#pragma unroll
    for (int kc = 0; kc < 2; kc++) {
        const float* p = in + (size_t)srow * 64 + kc * 32 + lk * 8;
        float4 v0 = *(const float4*)p;
        float4 v1 = *(const float4*)(p + 4);
        float vv[8] = {v0.x, v0.y, v0.z, v0.w, v1.x, v1.y, v1.z, v1.w};
        if (pre_flag) {
            const float* bp = b_pre + kc * 32 + lk * 8;
            float4 b0 = *(const float4*)bp;
            float4 b1 = *(const float4*)(bp + 4);
            float bb[8] = {b0.x, b0.y, b0.z, b0.w, b1.x, b1.y, b1.z, b1.w};
#pragma unroll
            for (int e = 0; e < 8; e++)
                vv[e] = fmaxf(fmaf(dv, vv[e], bb[e]), 0.f);
        }
#pragma unroll
        for (int e = 0; e < 8; e++) {
            unsigned short h = f2bf(vv[e]);
            ah[kc][e] = (short)h;
            al[kc][e] = (short)f2bf(vv[e] - bf2f(h));
        }
    }

    __syncthreads();

    f32x4 acc[4] = {};
#pragma unroll
    for (int ct = 0; ct < 4; ct++) {
#pragma unroll
        for (int kc = 0; kc < 2; kc++) {
            const short* ph = &Wh[(ct * 16 + lr) * WT_LD + kc * 32 + lk * 8];
            const short* pl = &Wl[(ct * 16 + lr) * WT_LD + kc * 32 + lk * 8];
            bf16x8 bh = *(const bf16x8*)ph;
            bf16x8 bl = *(const bf16x8*)pl;
            acc[ct] = __builtin_amdgcn_mfma_f32_16x16x32_bf16(ah[kc], bh, acc[ct], 0, 0, 0);
            acc[ct] = __builtin_amdgcn_mfma_f32_16x16x32_bf16(al[kc], bh, acc[ct], 0, 0, 0);
            acc[ct] = __builtin_amdgcn_mfma_f32_16x16x32_bf16(ah[kc], bl, acc[ct], 0, 0, 0);
            acc[ct] = __builtin_amdgcn_mfma_f32_16x16x32_bf16(al[kc], bl, acc[ct], 0, 0, 0);
        }
    }

    // store: D[row = row0 + lk*4 + r][col = ct*16 + lr]  (m89-verified C/D map)
#pragma unroll
    for (int r = 0; r < 4; r++) {
        int orow = row0 + lk * 4 + r;
        if (orow >= n_rows) continue;
        float sc = post_scale ? dinv[orow] : 1.0f;
#pragma unroll
        for (int ct = 0; ct < 4; ct++) {
            float bpv = b_post ? b_post[ct * 16 + lr] : 0.f;
            float o = fmaf(acc[ct][r], sc, bpv);
            if (out_bf16)
                ((unsigned short*)out1)[((size_t)orow << 6) + ct * 16 + lr] = f2bf(o);
            else
                ((float*)out1)[((size_t)orow << 6) + ct * 16 + lr] = o;
        }
    }
}

// Segmented reduction over dst-CSR: B[d] = A[d] + sum A[csr[e]]  (A is bf16).
// Eighth-wave (8 lanes) per node: lane owns uint4 (8 bf16 cols) of the row.
// Edge loop in explicit 8-edge register batches: 8 exec-masked gathers into
// vv[8] (zero-init), THEN accumulate (zero-adds for masked slots; ascending
// k = bitwise-identical order). Guarantees 8 loads in flight per wave (first
// acc waits vmcnt(7)). launch_bounds(256,8) pins VGPR<=64 -> 8 waves/SIMD.
__global__ __launch_bounds__(WG, 8) void aggregate(
    const uint4* __restrict__ A8, float* __restrict__ B,
    const int* __restrict__ off, const int* __restrict__ csr, int N)
{
    const int t = threadIdx.x;
    const int l = t & 63;
    const int c = l & 7;            // uint4 col (8 bf16 values)
    const int g = l >> 3;           // eighth = node sub-slot
    int node = blockIdx.x * 32 + ((t >> 6) << 3) + g;
    const bool valid = node < N;
    if (!valid) node = N - 1;

    const int s0 = off[node];
    const int s1 = valid ? off[node + 1] : s0;

    uint4 v = A8[((size_t)node << 3) + c];          // self-loop row
    float a0 = 0.f, a1 = 0.f, a2 = 0.f, a3 = 0.f;
    float a4 = 0.f, a5 = 0.f, a6 = 0.f, a7 = 0.f;
    acc_bf16x2(a0, a1, v.x);
    acc_bf16x2(a2, a3, v.y);
    acc_bf16x2(a4, a5, v.z);
    acc_bf16x2(a6, a7, v.w);

    for (int p = s0; p < s1; p += 32) {
        const int rem = s1 - p;
        int idx[4];
#pragma unroll
        for (int q = 0; q < 4; q++)
            idx[q] = (8 * q + c < rem) ? csr[p + 8 * q + c] : 0;  // batched
#pragma unroll
        for (int kb = 0; kb < 32; kb += 8) {
            if (kb < rem) {                   // batch live for this group?
                uint4 vv[8];
#pragma unroll
                for (int j = 0; j < 8; j++) {  // 8 gathers issued back-to-back
                    int k = kb + j;
                    int src = __shfl(idx[k >> 3], (g << 3) + (k & 7));
                    vv[j] = make_uint4(0u, 0u, 0u, 0u);
                    if (k < rem) vv[j] = A8[((size_t)src << 3) + c];
                }
#pragma unroll
                for (int j = 0; j < 8; j++) {  // dense accumulate (zero-adds ok)
                    acc_bf16x2(a0, a1, vv[j].x);
                    acc_bf16x2(a2, a3, vv[j].y);
                    acc_bf16x2(a4, a5, vv[j].z);
                    acc_bf16x2(a6, a7, vv[j].w);
                }
            }
        }
    }

    if (valid) {
        float* bp = B + ((size_t)node << 6) + 8 * c;
        *(float4*)bp       = make_float4(a0, a1, a2, a3);
        *(float4*)(bp + 4) = make_float4(a4, a5, a6, a7);
    }
}

extern "C" void kernel_launch(void* const* d_in, const int* in_sizes, int n_in,
                              void* d_out, int out_size, void* d_ws, size_t ws_size,
                              hipStream_t stream) {
    const float* x  = (const float*)d_in[0];
    const int*   ei = (const int*)d_in[1];
    const float* W1 = (const float*)d_in[2];
    const float* b1 = (const float*)d_in[3];
    const float* W2 = (const float*)d_in[4];
    const float* b2 = (const float*)d_in[5];
    const float* W3 = (const float*)d_in[6];
    const float* b3 = (const float*)d_in[7];
    float* out = (float*)d_out;

    const int N = in_sizes[0] / 64;    // 100000
    const int E = in_sizes[1] / 2;     // 1250000
    const int nbk = (N + BSIZE - 1) / BSIZE;        // 391 buckets

    // workspace layout
    int*   off  = (int*)d_ws;                       // N+1
    int*   csr  = off + (N + 1);                    // E
    int*   cur2 = csr + E;                          // 512 (bucket counts)
    uintptr_t pa = (uintptr_t)(cur2 + 512);
    pa = (pa + 255) & ~(uintptr_t)255;
    float* dinv = (float*)pa;                       // N
    __hip_bfloat16* A = (__hip_bfloat16*)(dinv + N);// N*64 bf16 (hs)
    float* B    = (float*)(A + (size_t)N * 64);     // N*64 fp32 (agg)
    unsigned* pairs = (unsigned*)B;                 // aliased: dead until agg1
                                                    // nbk*BCAP*4 = 6.4MB <= 25.6MB

    const int gG = (N + 63) / 64;
    const int gA = (N + 31) / 32;
    const int gP = (E + PCHUNK - 1) / PCHUNK;

    // CSR build (per call; ws re-poisoned every launch)
    (void)hipMemsetAsync(cur2, 0, 512 * sizeof(int), stream);
    partition<<<gP,  WG, 0, stream>>>(ei, cur2, pairs, E);
    csr_local<<<nbk, 512, 0, stream>>>(pairs, cur2, off, dinv, csr, N, nbk);

    // Layer 1: A = bf16(dinv.*(x@W1)); B = A[d] + sum A[src]
    gemm_fused<<<gG, WG, 0, stream>>>(x, W1, dinv, nullptr, 0, 1, nullptr, A, 1, N);
    aggregate <<<gA, WG, 0, stream>>>((const uint4*)A, B, off, csr, N);

    // Layer 2: in = B (pre: relu(dinv*v + b1)); A = bf16(dinv.*(h@W2)); B = agg
    gemm_fused<<<gG, WG, 0, stream>>>(B, W2, dinv, b1, 1, 1, nullptr, A, 1, N);
    aggregate <<<gA, WG, 0, stream>>>((const uint4*)A, B, off, csr, N);

    // Layer 3: in = B (pre: relu(dinv*v + b2)); out = h@W3 + b3 (fp32)
    gemm_fused<<<gG, WG, 0, stream>>>(B, W3, dinv, b2, 1, 0, b3, out, 0, N);
}

// Round 10
// 218.947 us; speedup vs baseline: 1.6126x; 1.4119x over previous
//
#include <hip/hip_runtime.h>
#include <hip/hip_bf16.h>

// GCN encoder: 3 layers on N=100000 nodes, E=1250000 edges, 64 features.
// gcn(x) = relu(D^-1/2 (A+I) D^-1/2 (xW) + b)
// Folding: hs = dinv .* (xW);  agg[d] = hs[d] + sum_{s->d} hs[s];
//          next layer's GEMM applies relu(dinv[d]*agg + b) as its pre-transform.
// R1..R8: dst-CSR gather reduction, bucketed 2-phase CSR build, bf16 hs,
//         split-bf16 MFMA GEMM (fp32-accurate), LDS-staged csr_local.
// R9 (REVERTED): agg+gemm fusion (latency-bound: parallelism > traffic cuts).
// R10: eighth-wave uint4 aggregate; 32b packed pairs; BSHIFT 8.
// R11: memset-based cursors; bsum_scan folded into csr_local; PCHUNK 3072.
//      == best verified state: 219.4 us ==
// R12-R14 (REVERTED): explicit vv[8] register-batched gathers (with or
//      without NT hints) spilled the batch to scratch under the 64-VGPR
//      budget: WRITE 25->116MB, FETCH 70->123MB, aggregate 28->80+us.
//      Lesson: per-wave MLP forced via register arrays loses to TLP here;
//      the low-VGPR guarded-load form at 8 waves/SIMD is the optimum.
// R15: exact revert of aggregate to the R10/R11 form.

#define WG 256
#define BSHIFT 8                 // 256 nodes per bucket
#define BSIZE  (1 << BSHIFT)
#define NBK_MAX 512
#define BCAP   4096              // pair slots per bucket (mean 3200, sd ~57)
#define PCHUNK 3072              // edges per partition block (12 per thread)
#define WT_LD  72                // transposed-W LDS leading dim (bf16 elems)

typedef __attribute__((ext_vector_type(8))) short bf16x8;
typedef __attribute__((ext_vector_type(4))) float f32x4;

__device__ __forceinline__ unsigned short f2bf(float f) {
    union { float f; unsigned u; } v; v.f = f;
    unsigned r = v.u + 0x7fffu + ((v.u >> 16) & 1u);   // RNE
    return (unsigned short)(r >> 16);
}
__device__ __forceinline__ float bf2f(unsigned short h) {
    union { unsigned u; float f; } v; v.u = ((unsigned)h) << 16;
    return v.f;
}
__device__ __forceinline__ void acc_bf16x2(float& a, float& b, unsigned u) {
    union { unsigned v; float f; } lo, hi;
    lo.v = u << 16;
    hi.v = u & 0xffff0000u;
    a += lo.f;
    b += hi.f;
}

// Partition edges by dst-bucket into packed pairs ((dst&255)<<17 | src) in
// fixed per-bucket slabs. cur2[b] holds the bucket COUNT (memset 0 before);
// slab position = b*BCAP + count. LDS histogram -> one global atomic per
// touched bucket -> stage (pair,dest) in LDS in bucket-slot order -> linear
// output loop: consecutive threads write consecutive dests per bucket run.
__global__ __launch_bounds__(WG) void partition(const int* __restrict__ ei,
                                                int* __restrict__ cur2,
                                                unsigned* __restrict__ pairs,
                                                int E) {
    __shared__ int hist[NBK_MAX];
    __shared__ int gbase[NBK_MAX];
    __shared__ int lb[NBK_MAX];
    __shared__ int wsum4[4];
    __shared__ unsigned sp[PCHUNK];
    __shared__ int sd[PCHUNK];
    const int t = threadIdx.x;
    const int lane = t & 63;
    const int w = t >> 6;
    const int base = blockIdx.x * PCHUNK;
    const int total = min(PCHUNK, E - base);

    hist[t] = 0;
    hist[t + 256] = 0;
    __syncthreads();

    int s[12], d[12], r[12];
#pragma unroll
    for (int i = 0; i < 12; i++) {
        int e = base + i * WG + t;           // coalesced
        bool ok = e < E;
        s[i] = ok ? ei[e] : 0;
        d[i] = ok ? ei[E + e] : 0;
        r[i] = ok ? atomicAdd(&hist[d[i] >> BSHIFT], 1) : 0;
        if (!ok) d[i] = -1;
    }
    __syncthreads();

    // per-bucket global base (buckets t and t+256): slab offset + old count
    int hv0 = hist[t];
    int hv1 = hist[t + 256];
    if (hv0 > 0) gbase[t] = t * BCAP + atomicAdd(&cur2[t], hv0);
    if (hv1 > 0) gbase[t + 256] = (t + 256) * BCAP + atomicAdd(&cur2[t + 256], hv1);

    // exclusive scan of hist[0..511] -> lb: thread t owns pair (2t, 2t+1)
    int a0 = hist[2 * t];
    int a1 = hist[2 * t + 1];
    int ps = a0 + a1;
    int sc = ps;
#pragma unroll
    for (int ofs = 1; ofs < 64; ofs <<= 1) {
        int u = __shfl_up(sc, ofs);
        if (lane >= ofs) sc += u;
    }
    if (lane == 63) wsum4[w] = sc;
    __syncthreads();
    if (t == 0) {
        int run = 0;
#pragma unroll
        for (int i = 0; i < 4; i++) { int x = wsum4[i]; wsum4[i] = run; run += x; }
    }
    __syncthreads();
    int excl = sc + wsum4[w] - ps;
    lb[2 * t] = excl;
    lb[2 * t + 1] = excl + a0;
    __syncthreads();

#pragma unroll
    for (int i = 0; i < 12; i++) {
        if (d[i] >= 0) {
            int b = d[i] >> BSHIFT;
            int slot = lb[b] + r[i];
            sp[slot] = ((unsigned)(d[i] & (BSIZE - 1)) << 17) | (unsigned)s[i];
            sd[slot] = gbase[b] + r[i];
        }
    }
    __syncthreads();

    for (int j = t; j < total; j += WG)
        pairs[sd[j]] = sp[j];
}

// Per-bucket CSR. Entry: every block shfl-scans the 512 bucket counts (cur2)
// to get its own global base (replaces the bsum_scan dispatch; block 0 also
// writes off[N]=E). Then: stage packed pairs (16KB) + bucket-local csr
// (16KB) in LDS, LDS hist/scatter, coalesced write-out. 391 blocks x 512
// threads, ~36KB LDS -> 4 blocks/CU.
__global__ __launch_bounds__(512) void csr_local(const unsigned* __restrict__ pairs,
                                                 const int* __restrict__ cur2,
                                                 int* __restrict__ off,
                                                 float* __restrict__ dinv,
                                                 int* __restrict__ csr,
                                                 int N, int nbk) {
    __shared__ unsigned sp[BCAP];             // 16 KB staged pairs
    __shared__ int cs[BCAP];                  // 16 KB bucket-local csr
    __shared__ int h[BSIZE];
    __shared__ int cur[BSIZE];
    __shared__ int bb[NBK_MAX];               // 2 KB exclusive bucket bases
    __shared__ int wsum8[8];
    __shared__ int wsum4[4];
    const int b = blockIdx.x;
    const int t = threadIdx.x;
    const int lane = t & 63;
    const int w = t >> 6;
    const int node0 = b << BSHIFT;
    const int nlocal = min(BSIZE, N - node0);
    const int pstart = b * BCAP;
    const int cnt = cur2[b];                  // count (memset-0 + atomics)

    // ---- bucket-base scan (all 512 counts), replaces bsum_scan ----
    int cval = (t < nbk) ? cur2[t] : 0;
    int sc2 = cval;
#pragma unroll
    for (int ofs = 1; ofs < 64; ofs <<= 1) {
        int u = __shfl_up(sc2, ofs);
        if (lane >= ofs) sc2 += u;
    }
    if (lane == 63) wsum8[w] = sc2;
    if (t < BSIZE) h[t] = 0;                  // hist init (no extra barrier)
    __syncthreads();
    if (t == 0) {
        int run = 0;
#pragma unroll
        for (int i = 0; i < 8; i++) { int x = wsum8[i]; wsum8[i] = run; run += x; }
    }
    __syncthreads();
    bb[t] = sc2 + wsum8[w] - cval;            // exclusive prefix
    if (b == 0 && t == 511) off[N] = sc2 + wsum8[7];   // total = E
    __syncthreads();
    const int base = bb[b];

    // ---- stage pairs + histogram ----
    for (int e = t; e < cnt; e += 512) {      // only global pairs read
        unsigned p = pairs[pstart + e];
        sp[e] = p;
        atomicAdd(&h[p >> 17], 1);
    }
    __syncthreads();

    // scan h[0..255]: waves 0..3 shfl scan + cross-wave fixup
    int myh = (t < BSIZE) ? h[t] : 0;
    int sc = myh;
#pragma unroll
    for (int d = 1; d < 64; d <<= 1) {
        int u = __shfl_up(sc, d);
        if (lane >= d) sc += u;
    }
    if (t < BSIZE && lane == 63) wsum4[w] = sc;
    __syncthreads();
    if (t == 0) {
        int run = 0;
#pragma unroll
        for (int i = 0; i < 4; i++) { int x = wsum4[i]; wsum4[i] = run; run += x; }
    }
    __syncthreads();
    if (t < BSIZE) {
        int excl = sc + wsum4[w] - myh;       // bucket-local exclusive prefix
        cur[t] = excl;
        if (t < nlocal) {
            off[node0 + t] = base + excl;
            dinv[node0 + t] = rsqrtf((float)(myh + 1));
        }
    }
    __syncthreads();

    for (int e = t; e < cnt; e += 512) {      // LDS scatter
        unsigned p = sp[e];
        int pos = atomicAdd(&cur[p >> 17], 1);
        cs[pos] = (int)(p & 0x1ffffu);
    }
    __syncthreads();

    for (int j = t; j < cnt; j += 512)        // coalesced write-out
        csr[base + j] = cs[j];
}

// Fused GEMM via split-bf16 MFMA: out = post( pre(in) @ W )
//   pre(v)  = pre_flag ? relu(dinv[row]*v + b_pre[col]) : v
//   post(a) = (post_scale ? dinv[row]*a : a) + (b_post ? b_post[col] : 0)
// Block = 64 rows x 64 cols, 4 waves x 16 rows; A-frags from global with
// pre-transform in fp32, split to bf16 hi/lo; W staged transposed hi/lo in
// LDS; 4 MFMAs per (ct,kc) reproduce fp32 accuracy at matrix-core rate.
__global__ __launch_bounds__(WG, 4) void gemm_fused(
    const float* __restrict__ in, const float* __restrict__ W,
    const float* __restrict__ dinv, const float* __restrict__ b_pre, int pre_flag,
    int post_scale, const float* __restrict__ b_post,
    void* __restrict__ out1, int out_bf16, int n_rows)
{
    __shared__ __align__(16) short Wh[64 * WT_LD];
    __shared__ __align__(16) short Wl[64 * WT_LD];

    const int t = threadIdx.x;

    // stage W transposed, split hi/lo bf16 (Wt[j][k], j = output col)
    const float4* W4 = (const float4*)W;
#pragma unroll
    for (int i = 0; i < 4; i++) {
        int q = i * WG + t;              // float4 index, 1024 total
        float4 w = W4[q];
        int base = q * 4;
        int k = base >> 6;
        int j0 = base & 63;
        float wf[4] = {w.x, w.y, w.z, w.w};
#pragma unroll
        for (int e = 0; e < 4; e++) {
            unsigned short h = f2bf(wf[e]);
            Wh[(j0 + e) * WT_LD + k] = (short)h;
            Wl[(j0 + e) * WT_LD + k] = (short)f2bf(wf[e] - bf2f(h));
        }
    }

    const int wid = t >> 6;              // wave 0..3
    const int l = t & 63;
    const int lr = l & 15;
    const int lk = l >> 4;
    const int row0 = blockIdx.x * 64 + wid * 16;
    const int arow = row0 + lr;
    const int srow = (arow < n_rows) ? arow : 0;   // safe row for loads

    // A fragments: 2 k-chunks of 32, pre-transform + hi/lo split
    bf16x8 ah[2], al[2];
    float dv = pre_flag ? dinv[srow] : 0.f;
#pragma unroll
    for (int kc = 0; kc < 2; kc++) {
        const float* p = in + (size_t)srow * 64 + kc * 32 + lk * 8;
        float4 v0 = *(const float4*)p;
        float4 v1 = *(const float4*)(p + 4);
        float vv[8] = {v0.x, v0.y, v0.z, v0.w, v1.x, v1.y, v1.z, v1.w};
        if (pre_flag) {
            const float* bp = b_pre + kc * 32 + lk * 8;
            float4 b0 = *(const float4*)bp;
            float4 b1 = *(const float4*)(bp + 4);
            float bb[8] = {b0.x, b0.y, b0.z, b0.w, b1.x, b1.y, b1.z, b1.w};
#pragma unroll
            for (int e = 0; e < 8; e++)
                vv[e] = fmaxf(fmaf(dv, vv[e], bb[e]), 0.f);
        }
#pragma unroll
        for (int e = 0; e < 8; e++) {
            unsigned short h = f2bf(vv[e]);
            ah[kc][e] = (short)h;
            al[kc][e] = (short)f2bf(vv[e] - bf2f(h));
        }
    }

    __syncthreads();

    f32x4 acc[4] = {};
#pragma unroll
    for (int ct = 0; ct < 4; ct++) {
#pragma unroll
        for (int kc = 0; kc < 2; kc++) {
            const short* ph = &Wh[(ct * 16 + lr) * WT_LD + kc * 32 + lk * 8];
            const short* pl = &Wl[(ct * 16 + lr) * WT_LD + kc * 32 + lk * 8];
            bf16x8 bh = *(const bf16x8*)ph;
            bf16x8 bl = *(const bf16x8*)pl;
            acc[ct] = __builtin_amdgcn_mfma_f32_16x16x32_bf16(ah[kc], bh, acc[ct], 0, 0, 0);
            acc[ct] = __builtin_amdgcn_mfma_f32_16x16x32_bf16(al[kc], bh, acc[ct], 0, 0, 0);
            acc[ct] = __builtin_amdgcn_mfma_f32_16x16x32_bf16(ah[kc], bl, acc[ct], 0, 0, 0);
            acc[ct] = __builtin_amdgcn_mfma_f32_16x16x32_bf16(al[kc], bl, acc[ct], 0, 0, 0);
        }
    }

    // store: D[row = row0 + lk*4 + r][col = ct*16 + lr]  (m89-verified C/D map)
#pragma unroll
    for (int r = 0; r < 4; r++) {
        int orow = row0 + lk * 4 + r;
        if (orow >= n_rows) continue;
        float sc = post_scale ? dinv[orow] : 1.0f;
#pragma unroll
        for (int ct = 0; ct < 4; ct++) {
            float bpv = b_post ? b_post[ct * 16 + lr] : 0.f;
            float o = fmaf(acc[ct][r], sc, bpv);
            if (out_bf16)
                ((unsigned short*)out1)[((size_t)orow << 6) + ct * 16 + lr] = f2bf(o);
            else
                ((float*)out1)[((size_t)orow << 6) + ct * 16 + lr] = o;
        }
    }
}

// Segmented reduction over dst-CSR: B[d] = A[d] + sum A[csr[e]]  (A is bf16).
// Eighth-wave (8 lanes) per node: lane owns uint4 (8 bf16 cols) of the row,
// one gather instruction covers 8 edge-rows. 32-deep unrolled edge loop with
// 4 batched index loads: one index round trip per node for deg<=32
// (P(deg>32) ~ 2e-6). Low-VGPR guarded-load form: TLP (8 waves/SIMD at
// VGPR~16) supplies the memory parallelism — register-batch variants spill
// to scratch and regress 3x (R12-R14). 8 consecutive nodes per wave ->
// 2KB contiguous wave store.
__global__ __launch_bounds__(WG) void aggregate(
    const uint4* __restrict__ A8, float* __restrict__ B,
    const int* __restrict__ off, const int* __restrict__ csr, int N)
{
    const int t = threadIdx.x;
    const int l = t & 63;
    const int c = l & 7;            // uint4 col (8 bf16 values)
    const int g = l >> 3;           // eighth = node sub-slot
    int node = blockIdx.x * 32 + ((t >> 6) << 3) + g;
    const bool valid = node < N;
    if (!valid) node = N - 1;

    const int s0 = off[node];
    const int s1 = valid ? off[node + 1] : s0;

    uint4 v = A8[((size_t)node << 3) + c];          // self-loop row
    float a0 = 0.f, a1 = 0.f, a2 = 0.f, a3 = 0.f;
    float a4 = 0.f, a5 = 0.f, a6 = 0.f, a7 = 0.f;
    acc_bf16x2(a0, a1, v.x);
    acc_bf16x2(a2, a3, v.y);
    acc_bf16x2(a4, a5, v.z);
    acc_bf16x2(a6, a7, v.w);

    for (int p = s0; p < s1; p += 32) {
        const int rem = s1 - p;
        int idx[4];
#pragma unroll
        for (int q = 0; q < 4; q++)
            idx[q] = (8 * q + c < rem) ? csr[p + 8 * q + c] : 0;  // batched
#pragma unroll
        for (int k = 0; k < 32; k++) {
            int src = __shfl(idx[k >> 3], (g << 3) + (k & 7));
            if (k < rem) {
                uint4 wv = A8[((size_t)src << 3) + c];
                acc_bf16x2(a0, a1, wv.x);
                acc_bf16x2(a2, a3, wv.y);
                acc_bf16x2(a4, a5, wv.z);
                acc_bf16x2(a6, a7, wv.w);
            }
        }
    }

    if (valid) {
        float* bp = B + ((size_t)node << 6) + 8 * c;
        *(float4*)bp       = make_float4(a0, a1, a2, a3);
        *(float4*)(bp + 4) = make_float4(a4, a5, a6, a7);
    }
}

extern "C" void kernel_launch(void* const* d_in, const int* in_sizes, int n_in,
                              void* d_out, int out_size, void* d_ws, size_t ws_size,
                              hipStream_t stream) {
    const float* x  = (const float*)d_in[0];
    const int*   ei = (const int*)d_in[1];
    const float* W1 = (const float*)d_in[2];
    const float* b1 = (const float*)d_in[3];
    const float* W2 = (const float*)d_in[4];
    const float* b2 = (const float*)d_in[5];
    const float* W3 = (const float*)d_in[6];
    const float* b3 = (const float*)d_in[7];
    float* out = (float*)d_out;

    const int N = in_sizes[0] / 64;    // 100000
    const int E = in_sizes[1] / 2;     // 1250000
    const int nbk = (N + BSIZE - 1) / BSIZE;        // 391 buckets

    // workspace layout
    int*   off  = (int*)d_ws;                       // N+1
    int*   csr  = off + (N + 1);                    // E
    int*   cur2 = csr + E;                          // 512 (bucket counts)
    uintptr_t pa = (uintptr_t)(cur2 + 512);
    pa = (pa + 255) & ~(uintptr_t)255;
    float* dinv = (float*)pa;                       // N
    __hip_bfloat16* A = (__hip_bfloat16*)(dinv + N);// N*64 bf16 (hs)
    float* B    = (float*)(A + (size_t)N * 64);     // N*64 fp32 (agg)
    unsigned* pairs = (unsigned*)B;                 // aliased: dead until agg1
                                                    // nbk*BCAP*4 = 6.4MB <= 25.6MB

    const int gG = (N + 63) / 64;
    const int gA = (N + 31) / 32;
    const int gP = (E + PCHUNK - 1) / PCHUNK;

    // CSR build (per call; ws re-poisoned every launch)
    (void)hipMemsetAsync(cur2, 0, 512 * sizeof(int), stream);
    partition<<<gP,  WG, 0, stream>>>(ei, cur2, pairs, E);
    csr_local<<<nbk, 512, 0, stream>>>(pairs, cur2, off, dinv, csr, N, nbk);

    // Layer 1: A = bf16(dinv.*(x@W1)); B = A[d] + sum A[src]
    gemm_fused<<<gG, WG, 0, stream>>>(x, W1, dinv, nullptr, 0, 1, nullptr, A, 1, N);
    aggregate <<<gA, WG, 0, stream>>>((const uint4*)A, B, off, csr, N);

    // Layer 2: in = B (pre: relu(dinv*v + b1)); A = bf16(dinv.*(h@W2)); B = agg
    gemm_fused<<<gG, WG, 0, stream>>>(B, W2, dinv, b1, 1, 1, nullptr, A, 1, N);
    aggregate <<<gA, WG, 0, stream>>>((const uint4*)A, B, off, csr, N);

    // Layer 3: in = B (pre: relu(dinv*v + b2)); out = h@W3 + b3 (fp32)
    gemm_fused<<<gG, WG, 0, stream>>>(B, W3, dinv, b2, 1, 0, b3, out, 0, N);
}